// Round 9
// baseline (285.043 us; speedup 1.0000x reference)
//
#include <hip/hip_runtime.h>
#include <hip/hip_bf16.h>
#include <cstdint>
#include <cstddef>

typedef __attribute__((ext_vector_type(8))) __bf16 bf16x8;
typedef __attribute__((ext_vector_type(4))) float f32x4;
typedef __attribute__((ext_vector_type(16))) float f32x16;

#define MFMA16(a, b, c) __builtin_amdgcn_mfma_f32_16x16x32_bf16((a), (b), (c), 0, 0, 0)
#define MFMA32(a, b, c) __builtin_amdgcn_mfma_f32_32x32x16_bf16((a), (b), (c), 0, 0, 0)

__device__ __forceinline__ f32x16 zf16() {
    f32x16 z;
    #pragma unroll
    for (int r = 0; r < 16; ++r) z[r] = 0.f;
    return z;
}

__device__ __forceinline__ unsigned pk2(float lo, float hi) {
    unsigned w;
    asm("v_cvt_pk_bf16_f32 %0, %1, %2" : "=v"(w) : "v"(lo), "v"(hi));
    return w;
}
__device__ __forceinline__ void swap32(unsigned& a, unsigned& b) {
    asm("v_permlane32_swap_b32 %0, %1" : "+v"(a), "+v"(b));
}
__device__ __forceinline__ bf16x8 mkfrag(unsigned a, unsigned b, unsigned c, unsigned d) {
    union { unsigned u[4]; bf16x8 v; } x;
    x.u[0] = a; x.u[1] = b; x.u[2] = c; x.u[3] = d;
    return x.v;
}

// ---------------------------------------------------------------------------
// prep (fused): blocks 0..511 = x transpose+cvt; 512..639 = VO transpose;
// 640..895 = Q/K weight cvt (Q scaled by log2e/16).
// ---------------------------------------------------------------------------
__global__ __launch_bounds__(256) void prep(const float* __restrict__ x,
                                            const float* __restrict__ Qw,
                                            const float* __restrict__ Kw,
                                            const float* __restrict__ VO,
                                            __bf16* __restrict__ xT,
                                            __bf16* __restrict__ xrow,
                                            __bf16* __restrict__ wb,
                                            __bf16* __restrict__ vot) {
    __shared__ float tile[64][65];
    const int bid = blockIdx.x;
    if (bid < 512) {
        const int b = bid >> 8;
        const int rem = bid & 255;
        const int tt = rem >> 2, dd = rem & 3;
        const int t0 = tt * 64, d0 = dd * 64;
        #pragma unroll
        for (int j = 0; j < 16; ++j) {
            int idx = j * 256 + threadIdx.x;
            int t = idx >> 6, d = idx & 63;
            float v = x[((size_t)(b * 4096 + t0 + t)) * 256 + d0 + d];
            tile[t][d] = v;
            xrow[((size_t)(b * 4096 + t0 + t)) * 256 + d0 + d] = (__bf16)v;
        }
        __syncthreads();
        #pragma unroll
        for (int j = 0; j < 16; ++j) {
            int idx = j * 256 + threadIdx.x;
            int d = idx >> 6, t = idx & 63;
            xT[((size_t)(b * 256 + d0 + d)) * 4096 + t0 + t] = (__bf16)tile[t][d];
        }
    } else if (bid < 640) {
        const int k = bid - 512;
        const int h = k >> 4;
        const int rem = k & 15;
        const int dt = rem >> 2, et = rem & 3;
        const int d0 = dt * 64, e0 = et * 64;
        #pragma unroll
        for (int j = 0; j < 16; ++j) {
            int idx = j * 256 + threadIdx.x;
            int d = idx >> 6, e = idx & 63;
            tile[d][e] = VO[((size_t)(h * 256 + d0 + d)) * 256 + e0 + e];
        }
        __syncthreads();
        #pragma unroll
        for (int j = 0; j < 16; ++j) {
            int idx = j * 256 + threadIdx.x;
            int e = idx >> 6, d = idx & 63;
            vot[((size_t)(e0 + e)) * 2048 + h * 256 + d0 + d] = (__bf16)tile[d][e];
        }
    } else {
        const float cl = 1.4426950408889634f / 16.0f;
        #pragma unroll
        for (int e = 0; e < 2; ++e) {
            int i = (bid - 640) * 512 + e * 256 + threadIdx.x;
            float v = (i < 65536) ? Qw[i] * cl : Kw[i - 65536];
            wb[i] = (__bf16)v;
        }
    }
}

// ---------------------------------------------------------------------------
// proj: block = 64 t-rows (4 waves x 16 rows); wave keeps its 16-row x
// A-fragments in registers and loops all 16 (h,s) tasks (weights bf16).
// ---------------------------------------------------------------------------
__global__ __launch_bounds__(256) void proj_kernel(const __bf16* __restrict__ xrow,
                                                   const __bf16* __restrict__ wb,
                                                   __bf16* __restrict__ qo,
                                                   __bf16* __restrict__ ko) {
    const int w = threadIdx.x >> 6;
    const int l = threadIdx.x & 63;
    const int g = l >> 4, c = l & 15;
    const int tg = blockIdx.x * 64 + w * 16;

    bf16x8 af[8];
    #pragma unroll
    for (int kk = 0; kk < 8; ++kk)
        af[kk] = *(const bf16x8*)(xrow + (size_t)(tg + c) * 256 + kk * 32 + g * 8);

    const int b = tg >> 12, t = tg & 4095;
    #pragma unroll
    for (int hs = 0; hs < 16; ++hs) {
        const int h = hs >> 1, s = hs & 1;
        const __bf16* W = wb + (size_t)(s * 8 + h) * 8192;  // [32][256]
        f32x4 acc0 = {0.f, 0.f, 0.f, 0.f}, acc1 = {0.f, 0.f, 0.f, 0.f};
        #pragma unroll
        for (int kk = 0; kk < 8; ++kk) {
            bf16x8 b0 = *(const bf16x8*)(W + (size_t)c * 256 + kk * 32 + g * 8);
            bf16x8 b1 = *(const bf16x8*)(W + (size_t)(16 + c) * 256 + kk * 32 + g * 8);
            acc0 = MFMA16(af[kk], b0, acc0);
            acc1 = MFMA16(af[kk], b1, acc1);
        }
        __bf16* outp = s ? ko : qo;
        const size_t obase = (size_t)(b * 8 + h) * 4096 + t;
        #pragma unroll
        for (int i = 0; i < 4; ++i) {
            outp[(obase + 4 * g + i) * 32 + c]      = (__bf16)acc0[i];
            outp[(obase + 4 * g + i) * 32 + 16 + c] = (__bf16)acc1[i];
        }
    }
}

// ---------------------------------------------------------------------------
// attn v9: wave = 64 q-rows x 128 d-cols. 8 waves = 4 q-groups x 2 d-halves.
// Each x B-fragment feeds TWO PV MFMAs (both q-halves) -> LDS reads halved
// vs v8 (16 b128/wave/tile). QK + softmax computed redundantly per d-half
// (VALU/MFMA have slack; LDS is the bottleneck pipe). No-max softmax (v8).
// grid = 256 blocks x 512 threads (1 block/CU)
// ---------------------------------------------------------------------------
__device__ __forceinline__ void stage_x(const __bf16* __restrict__ xTg_b,
                                        unsigned char* xbuf, int u0, int tid) {
    #pragma unroll
    for (int j = 0; j < 4; ++j) {
        int ch = j * 512 + tid;
        int d = ch >> 3;
        int slog = (ch & 7) ^ (d & 7);
        const __bf16* src = xTg_b + (size_t)d * 4096 + u0 + slog * 8;
        unsigned char* dst = xbuf + (size_t)(j * 512 + (tid & ~63)) * 16;  // wave-uniform
        __builtin_amdgcn_global_load_lds(
            (const __attribute__((address_space(1))) unsigned int*)src,
            (__attribute__((address_space(3))) unsigned int*)dst, 16, 0, 0);
    }
}

#define MKFRAG(dst, V, base)                                   \
    {                                                          \
        unsigned wa = pk2(V[(base) + 0], V[(base) + 1]);       \
        unsigned wb_ = pk2(V[(base) + 2], V[(base) + 3]);      \
        unsigned wc = pk2(V[(base) + 4], V[(base) + 5]);       \
        unsigned wd = pk2(V[(base) + 6], V[(base) + 7]);       \
        swap32(wa, wc);                                        \
        swap32(wb_, wd);                                       \
        dst = mkfrag(wa, wb_, wc, wd);                         \
    }

__global__ __launch_bounds__(512, 2) void attn_kernel(const __bf16* __restrict__ qg,
                                                      const __bf16* __restrict__ kg,
                                                      const __bf16* __restrict__ xTg,
                                                      __bf16* __restrict__ ctx) {
    __shared__ __align__(16) unsigned char lds[65536 + 2048];
    unsigned char* xbuf0 = lds;
    unsigned char* xbuf1 = lds + 32768;

    const int bid = blockIdx.x;
    const int bh = bid >> 4;
    const int tt = bid & 15;
    const int b = bh >> 3, h = bh & 7;
    const int t0 = tt * 256;
    const int tid = threadIdx.x;
    const int w = tid >> 6;
    const int qgi = w >> 1;          // q-group 0..3 (64 rows each)
    const int dh = w & 1;            // d-half 0..1 (128 cols each)
    const int l = tid & 63;
    const int l31 = l & 31, hi = l >> 5;

    float* scale_w = (float*)(lds + 65536) + w * 64;

    const __bf16* xTg_b = xTg + (size_t)b * 256 * 4096;
    const __bf16* kg_bh = kg + (size_t)bh * 4096 * 32;

    // Q B-fragments: qf[qh][st] for q = t0 + qgi*64 + qh*32 + l31
    bf16x8 qf[2][2];
    #pragma unroll
    for (int qh = 0; qh < 2; ++qh) {
        const size_t qoff = ((size_t)bh * 4096 + t0 + qgi * 64 + qh * 32 + l31) * 32;
        qf[qh][0] = *(const bf16x8*)(qg + qoff + hi * 8);
        qf[qh][1] = *(const bf16x8*)(qg + qoff + 16 + hi * 8);
    }

    f32x16 acc[2][4];
    #pragma unroll
    for (int qh = 0; qh < 2; ++qh)
        #pragma unroll
        for (int n = 0; n < 4; ++n)
            acc[qh][n] = zf16();

    float lsum0 = 0.f, lsum1 = 0.f;
    const int swz = (l31 & 7) << 4;

    bf16x8 kA[2][2];
    #pragma unroll
    for (int s = 0; s < 2; ++s)
        #pragma unroll
        for (int st = 0; st < 2; ++st)
            kA[s][st] = *(const bf16x8*)(kg_bh + (size_t)(s * 32 + l31) * 32 + st * 16 + hi * 8);

    stage_x(xTg_b, xbuf0, 0, tid);
    __syncthreads();

    for (int ut = 0; ut < 64; ++ut) {
        unsigned char* xcur = (ut & 1) ? xbuf1 : xbuf0;
        unsigned char* xnxt = (ut & 1) ? xbuf0 : xbuf1;
        if (ut < 63) stage_x(xTg_b, xnxt, (ut + 1) * 64, tid);

        // ---- S^T = K * Q^T for 64 q x 64 u (log2-domain, scale in Q) ----
        f32x16 s00 = MFMA32(kA[0][0], qf[0][0], zf16());
        s00 = MFMA32(kA[0][1], qf[0][1], s00);
        f32x16 s01 = MFMA32(kA[1][0], qf[0][0], zf16());
        s01 = MFMA32(kA[1][1], qf[0][1], s01);
        f32x16 s10 = MFMA32(kA[0][0], qf[1][0], zf16());
        s10 = MFMA32(kA[0][1], qf[1][1], s10);
        f32x16 s11 = MFMA32(kA[1][0], qf[1][0], zf16());
        s11 = MFMA32(kA[1][1], qf[1][1], s11);

        if (ut < 63) {  // prefetch next k-tile fragments (4 loads)
            const __bf16* kp = kg_bh + (size_t)(ut + 1) * 64 * 32;
            #pragma unroll
            for (int s = 0; s < 2; ++s)
                #pragma unroll
                for (int st = 0; st < 2; ++st)
                    kA[s][st] = *(const bf16x8*)(kp + (size_t)(s * 32 + l31) * 32 + st * 16 + hi * 8);
        }

        // ---- P = exp2(S), per-lane sums (no max: scores bounded ~|5|) ----
        float rs0 = 0.f, rs1 = 0.f;
        #pragma unroll
        for (int r = 0; r < 16; ++r) {
            float p;
            p = __builtin_amdgcn_exp2f(s00[r]); s00[r] = p; rs0 += p;
            p = __builtin_amdgcn_exp2f(s01[r]); s01[r] = p; rs0 += p;
            p = __builtin_amdgcn_exp2f(s10[r]); s10[r] = p; rs1 += p;
            p = __builtin_amdgcn_exp2f(s11[r]); s11[r] = p; rs1 += p;
        }
        lsum0 += rs0;
        lsum1 += rs1;

        // ---- P -> A-frags per q-half: pfq[qh][kk], kk = 16-u chunk ----
        bf16x8 pf0[4], pf1[4];
        MKFRAG(pf0[0], s00, 0);
        MKFRAG(pf0[1], s00, 8);
        MKFRAG(pf0[2], s01, 0);
        MKFRAG(pf0[3], s01, 8);
        MKFRAG(pf1[0], s10, 0);
        MKFRAG(pf1[1], s10, 8);
        MKFRAG(pf1[2], s11, 0);
        MKFRAG(pf1[3], s11, 8);

        // ---- PV: each xb feeds both q-halves (16 b128 reads, 32 MFMA) ----
        __builtin_amdgcn_s_setprio(1);
        #pragma unroll
        for (int kk = 0; kk < 4; ++kk) {
            #pragma unroll
            for (int n = 0; n < 4; ++n) {
                const bf16x8 xb = *(const bf16x8*)(xcur +
                    (dh * 128 + n * 32 + l31) * 128 + ((kk * 32 + hi * 16) ^ swz));
                acc[0][n] = MFMA32(pf0[kk], xb, acc[0][n]);
                acc[1][n] = MFMA32(pf1[kk], xb, acc[1][n]);
            }
        }
        __builtin_amdgcn_s_setprio(0);

        // counted barrier: drain the 4 stage loads, keep kA prefetch in flight
        asm volatile("s_waitcnt vmcnt(4)" ::: "memory");
        __builtin_amdgcn_s_barrier();
    }

    // ---- epilogue: combine lsum halves, broadcast 1/lsum by q-row ----
    lsum0 += __shfl_xor(lsum0, 32);
    lsum1 += __shfl_xor(lsum1, 32);
    if (!hi) {
        scale_w[l31]      = 1.0f / lsum0;
        scale_w[32 + l31] = 1.0f / lsum1;
    }
    #pragma unroll
    for (int qh = 0; qh < 2; ++qh) {
        f32x4 iv[4];
        #pragma unroll
        for (int q4 = 0; q4 < 4; ++q4)
            iv[q4] = *(const f32x4*)&scale_w[qh * 32 + q4 * 8 + hi * 4];
        #pragma unroll
        for (int n = 0; n < 4; ++n) {
            #pragma unroll
            for (int r = 0; r < 16; ++r) {
                int t = t0 + qgi * 64 + qh * 32 + (r & 3) + 8 * (r >> 2) + 4 * hi;
                int d = dh * 128 + n * 32 + l31;
                ctx[((size_t)(b * 4096 + t) * 8 + h) * 256 + d] =
                    (__bf16)(acc[qh][n][r] * iv[r >> 2][r & 3]);
            }
        }
    }
}

// ---------------------------------------------------------------------------
// gemm_out: out[bt][e] = sum_k ctx[bt][k] * VOT[e][k]; M=8192 K=2048 N=256.
// block = 64 m-rows x 128 e (4 waves; wave = 2 m-tiles x 32 e).
// ---------------------------------------------------------------------------
__global__ __launch_bounds__(256) void gemm_out(const __bf16* __restrict__ ctx,
                                                const __bf16* __restrict__ vot,
                                                float* __restrict__ out) {
    const int bid = blockIdx.x;
    const int mt2 = bid >> 1;
    const int eh = bid & 1;
    const int w = threadIdx.x >> 6;
    const int l = threadIdx.x & 63;
    const int l31 = l & 31, hi = l >> 5;
    const size_t a0row = (size_t)(mt2 * 64 + l31) * 2048;
    const size_t a1row = (size_t)(mt2 * 64 + 32 + l31) * 2048;
    const size_t brow  = (size_t)(eh * 128 + w * 32 + l31) * 2048;
    f32x16 acc0 = zf16(), acc1 = zf16();
    #pragma unroll 4
    for (int kk = 0; kk < 128; ++kk) {
        bf16x8 bfr = *(const bf16x8*)(vot + brow + kk * 16 + hi * 8);
        bf16x8 a0  = *(const bf16x8*)(ctx + a0row + kk * 16 + hi * 8);
        bf16x8 a1  = *(const bf16x8*)(ctx + a1row + kk * 16 + hi * 8);
        acc0 = MFMA32(a0, bfr, acc0);
        acc1 = MFMA32(a1, bfr, acc1);
    }
    const int e = eh * 128 + w * 32 + l31;
    #pragma unroll
    for (int r = 0; r < 16; ++r) {
        int crow = (r & 3) + 8 * (r >> 2) + 4 * hi;
        out[(size_t)(mt2 * 64 + crow) * 256 + e]      = acc0[r];
        out[(size_t)(mt2 * 64 + 32 + crow) * 256 + e] = acc1[r];
    }
}

// ---------------------------------------------------------------------------
extern "C" void kernel_launch(void* const* d_in, const int* in_sizes, int n_in,
                              void* d_out, int out_size, void* d_ws, size_t ws_size,
                              hipStream_t stream) {
    const float* x  = (const float*)d_in[0];  // [2][4096][256]
    const float* Qw = (const float*)d_in[1];  // [8][32][256]
    const float* Kw = (const float*)d_in[2];  // [8][32][256]
    const float* VO = (const float*)d_in[3];  // [8][256][256]
    float* out = (float*)d_out;               // [2][4096][256]

    char* ws = (char*)d_ws;
    __bf16* xT   = (__bf16*)(ws);                          // 4 MB  [2][256][4096]
    __bf16* xrow = (__bf16*)(ws + ((size_t)4 << 20));      // 4 MB  [2][4096][256]
    __bf16* qb   = (__bf16*)(ws + ((size_t)8 << 20));      // 4 MB  [2][8][4096][32]
    __bf16* kb   = (__bf16*)(ws + ((size_t)12 << 20));     // 4 MB
    __bf16* wb   = (__bf16*)(ws + ((size_t)16 << 20));     // 256 KB [2][8][32][256]
    __bf16* vot  = (__bf16*)(ws + ((size_t)17 << 20));     // 1 MB  [256][2048]
    __bf16* ctx  = (__bf16*)(ws + ((size_t)18 << 20));     // 32 MB [2][4096][8][256]

    prep<<<896, 256, 0, stream>>>(x, Qw, Kw, VO, xT, xrow, wb, vot);
    proj_kernel<<<128, 256, 0, stream>>>(xrow, wb, qb, kb);
    attn_kernel<<<256, 512, 0, stream>>>(qb, kb, xT, ctx);
    gemm_out<<<256, 256, 0, stream>>>(ctx, vot, out);
}